// Round 6
// baseline (543.394 us; speedup 1.0000x reference)
//
#include <hip/hip_runtime.h>
#include <hip/hip_bf16.h>

// DeepSeek V3 MLA attention forward, MI355X (gfx950).
// B=2, S=2048, D=2048, H=16, NOPE=128, ROPE=64, VDIM=128, QKD=192.

typedef __bf16 bf16x8 __attribute__((ext_vector_type(8)));
typedef float floatx4 __attribute__((ext_vector_type(4)));
#define BF16 __hip_bfloat16

static __device__ __forceinline__ BF16 f2b(float x) { return __float2bfloat16(x); }
static __device__ __forceinline__ unsigned short b2u(BF16 x) { return *(unsigned short*)&x; }
static __device__ __forceinline__ float fast_exp2(float x) { return __builtin_amdgcn_exp2f(x); }

static __device__ __forceinline__ void load_lds16(const BF16* g, BF16* l) {
  __builtin_amdgcn_global_load_lds((__attribute__((address_space(1))) void*)(void*)g,
                                   (__attribute__((address_space(3))) void*)(void*)l,
                                   16, 0, 0);
}

// ---------------------------------------------------------------- multi-region cast f32->bf16
struct CastArgs {
  const float* src[6];
  BF16* dst[6];
  long n[6];
};
__global__ void cast_multi_k(CastArgs a) {
  int r = blockIdx.y;
  long n = a.n[r];
  const float* __restrict__ x = a.src[r];
  BF16* __restrict__ y = a.dst[r];
  for (long i = ((long)blockIdx.x * 256 + threadIdx.x) * 4; i + 3 < n;
       i += (long)gridDim.x * 1024) {
    float4 v = *(const float4*)(x + i);
    y[i+0] = f2b(v.x); y[i+1] = f2b(v.y); y[i+2] = f2b(v.z); y[i+3] = f2b(v.w);
  }
}

// ---------------------------------------------------------------- NT GEMM, m97-style LDS staging
// C[M][N] = A[M][K]*B[N][K]^T. 256 thr = 4 waves (2x2), 128x128 tile, BK=32.
// OUT_MODE: 0 = fp32 C;  2 = kv scatter -> Kt (scalar) / Vt transposed (8B packed);
//           3 = q RoPE+scale scatter -> Qt (scale includes log2(e) for exp2 softmax).
template<int OUT_MODE>
__global__ __launch_bounds__(256) void gemm_lds(const BF16* __restrict__ A, const BF16* __restrict__ B,
                                                void* __restrict__ C, int M, int N, int K,
                                                const float* __restrict__ cosb,
                                                const float* __restrict__ sinb,
                                                BF16* __restrict__ P1, BF16* __restrict__ P2) {
  __shared__ __align__(16) BF16 As[128*32];
  __shared__ __align__(16) BF16 Bs[128*32];
  int tid = threadIdx.x, wave = tid >> 6, lane = tid & 63;
  int wr = wave >> 1, wc = wave & 1, lr = lane & 15, quad = lane >> 4;
  long m0 = (long)blockIdx.y * 128, n0 = (long)blockIdx.x * 128;

  int c0 = wave*64 + lane, c1 = c0 + 256;
  const BF16* ga0 = A + (m0 + (c0>>2))*(long)K + (c0&3)*8;
  const BF16* ga1 = A + (m0 + (c1>>2))*(long)K + (c1&3)*8;
  long bn0 = n0 + (c0>>2); if (bn0 >= N) bn0 = N-1;
  long bn1 = n0 + (c1>>2); if (bn1 >= N) bn1 = N-1;
  const BF16* gb0 = B + bn0*(long)K + (c0&3)*8;
  const BF16* gb1 = B + bn1*(long)K + (c1&3)*8;
  BF16* la0 = As + wave*512;
  BF16* la1 = As + wave*512 + 2048;
  BF16* lb0 = Bs + wave*512;
  BF16* lb1 = Bs + wave*512 + 2048;

  floatx4 acc[4][4] = {};
  for (int k0 = 0; k0 < K; k0 += 32) {
    __syncthreads();
    load_lds16(ga0 + k0, la0);
    load_lds16(ga1 + k0, la1);
    load_lds16(gb0 + k0, lb0);
    load_lds16(gb1 + k0, lb1);
    __syncthreads();
    bf16x8 a[4], b[4];
#pragma unroll
    for (int i = 0; i < 4; i++) a[i] = *(const bf16x8*)(As + (wr*64 + i*16 + lr)*32 + quad*8);
#pragma unroll
    for (int j = 0; j < 4; j++) b[j] = *(const bf16x8*)(Bs + (wc*64 + j*16 + lr)*32 + quad*8);
#pragma unroll
    for (int i = 0; i < 4; i++)
#pragma unroll
      for (int j = 0; j < 4; j++)
        acc[i][j] = __builtin_amdgcn_mfma_f32_16x16x32_bf16(a[i], b[j], acc[i][j], 0, 0, 0);
  }

  long n0w = n0 + wc*64;
  // 192^-0.5 * log2(e): softmax runs in exp2 domain.
  const float SCALE_L2E = 0.104117546f;
#pragma unroll
  for (int i = 0; i < 4; i++) {
    long tok = m0 + wr*64 + i*16 + quad*4;   // 4 consecutive tokens (r=0..3)
    long bb = tok >> 11, s = tok & 2047;
    if (OUT_MODE == 0) {
#pragma unroll
      for (int r = 0; r < 4; r++) {
        long row = tok + r;
#pragma unroll
        for (int j = 0; j < 4; j++) {
          long col = n0w + j*16 + lr;
          if (col < N) ((float*)C)[row*(long)N + col] = acc[i][j][r];
        }
      }
    } else if (OUT_MODE == 2) {
#pragma unroll
      for (int j = 0; j < 4; j++) {
        long col = n0w + j*16 + lr;
        long h = col >> 8, d = col & 255;
        if (d < 128) {
#pragma unroll
          for (int r = 0; r < 4; r++)
            P1[((bb*16 + h)*2048 + s + r)*192 + d] = f2b(acc[i][j][r]);
        } else {
          // Vt transposed (B,H,128,2048): 4 consecutive tokens packed, 8B store
          ushort4 pk;
          pk.x = b2u(f2b(acc[i][j][0])); pk.y = b2u(f2b(acc[i][j][1]));
          pk.z = b2u(f2b(acc[i][j][2])); pk.w = b2u(f2b(acc[i][j][3]));
          *(ushort4*)(P2 + ((bb*16 + h)*128 + d - 128)*2048 + s) = pk;
        }
      }
    } else { // OUT_MODE == 3: q RoPE + scale -> Qt (B,H,S,192)
      bool rope = ((n0w % 192) == 128);
#pragma unroll
      for (int r = 0; r < 4; r++) {
        long row = tok + r;
#pragma unroll
        for (int j = 0; j < 4; j++) {
          long col = n0w + j*16 + lr;
          float x = acc[i][j][r], val;
          if (rope) {
            int id = j*16 + lr;
            float partner = acc[i][j^2][r];
            float rot = (j < 2) ? -partner : partner;
            val = x*cosb[row*64 + id] + rot*sinb[row*64 + id];
          } else {
            val = x;
          }
          long h = col / 192, d = col % 192;
          P1[((bb*16 + h)*2048 + s + r)*192 + d] = f2b(val * SCALE_L2E);
        }
      }
    }
  }
}

// ---------------------------------------------------------------- RMSNorm (row-wise), fp32 in, bf16 out
template<int D>
__global__ __launch_bounds__(256) void rmsnorm_k(const float* __restrict__ x, const float* __restrict__ w,
                                                 BF16* __restrict__ y, int ld_in, int ld_out) {
  long row = blockIdx.x;
  const float* xr = x + row * (long)ld_in;
  float ss = 0.f;
  for (int i = threadIdx.x * 4; i < D; i += 1024) {
    float4 v = *(const float4*)(xr + i);
    ss += v.x*v.x + v.y*v.y + v.z*v.z + v.w*v.w;
  }
#pragma unroll
  for (int off = 32; off > 0; off >>= 1) ss += __shfl_down(ss, off);
  __shared__ float red[4];
  if ((threadIdx.x & 63) == 0) red[threadIdx.x >> 6] = ss;
  __syncthreads();
  float tot = red[0] + red[1] + red[2] + red[3];
  float rs = rsqrtf(tot / (float)D + 1e-6f);
  BF16* yr = y + row * (long)ld_out;
  for (int i = threadIdx.x * 4; i < D; i += 1024) {
    float4 v = *(const float4*)(xr + i);
    yr[i+0] = f2b(v.x * w[i+0] * rs);
    yr[i+1] = f2b(v.y * w[i+1] * rs);
    yr[i+2] = f2b(v.z * w[i+2] * rs);
    yr[i+3] = f2b(v.w * w[i+3] * rs);
  }
}

// ---------------------------------------------------------------- RoPE on k_rot -> Kt[...,128:192] for all 16 heads
__global__ void prep_krot_k(const float* __restrict__ krot, int ld, const float* __restrict__ cosb,
                            const float* __restrict__ sinb, BF16* __restrict__ Kt) {
  long row = blockIdx.x; int i = threadIdx.x;
  const float* kr = krot + row * (long)ld;
  float x = kr[i];
  float rot = (i < 32) ? -kr[i + 32] : kr[i - 32];
  BF16 v = f2b(x * cosb[row*64 + i] + rot * sinb[row*64 + i]);
  long b = row >> 11, s = row & 2047;
  long base = ((b*16)*2048 + s)*192 + 128 + i;
#pragma unroll
  for (int h = 0; h < 16; h++) Kt[base + (long)h*2048*192] = v;
}

// ---------------------------------------------------------------- causal flash attention
// flat grid 512; g = F&31 = (b,h) group (pins group to XCD F%8); qti = 15-(F>>5)
// (LPT: longest q-tiles dispatch first -> near-optimal per-XCD packing, ~34 iters/CU).
// 128-row q-tile per block; each wave owns 2x16 rows (fragments s=0,1 at +0/+64).
// Q prescaled by 192^-0.5*log2e -> exp2 softmax. V stored transposed (B,H,128,S).
#define LK 200
#define LV 72
#define LP 72
__global__ __launch_bounds__(256, 2) void flash_k(const BF16* __restrict__ Qt, const BF16* __restrict__ Kt,
                                                  const BF16* __restrict__ Vt, BF16* __restrict__ O) {
  __shared__ __align__(16) BF16 Ks[64*LK];    // K tile [kpos][d]
  __shared__ __align__(16) BF16 Vs[128*LV];   // V^T tile [vd][kpos]
  __shared__ __align__(16) BF16 Ps[4][16*LP]; // per-wave P fragment [q16][kpos]
  int tid = threadIdx.x, wave = tid >> 6, lane = tid & 63;
  int lr = lane & 15, quad = lane >> 4;
  int F = blockIdx.x;
  int g = F & 31, qti = 15 - (F >> 5);
  int h = g & 15, b = g >> 4;
  const BF16* Qb = Qt + ((long)(b*16 + h) * 2048) * 192;
  const BF16* Kb = Kt + ((long)(b*16 + h) * 2048) * 192;
  const BF16* Vb = Vt + ((long)(b*16 + h) * 128) * 2048;
  const float NEG_INF = -__builtin_inff();
  int q0 = qti * 128;

  // staging geometry
  int krow[6], kcol[6];
#pragma unroll
  for (int i = 0; i < 6; i++) {
    int c = tid + 256*i;
    krow[i] = c / 24; kcol[i] = (c % 24) * 8;
  }
  int vrow[4], vcol[4];
#pragma unroll
  for (int i = 0; i < 4; i++) {
    int c = tid + 256*i;
    vrow[i] = c >> 3; vcol[i] = (c & 7) * 8;
  }

  bf16x8 kreg[6], vreg[4];
  auto stage_load = [&](int k0) {
#pragma unroll
    for (int i = 0; i < 6; i++)
      kreg[i] = *(const bf16x8*)(Kb + (long)(k0 + krow[i])*192 + kcol[i]);
#pragma unroll
    for (int i = 0; i < 4; i++)
      vreg[i] = *(const bf16x8*)(Vb + (long)vrow[i]*2048 + k0 + vcol[i]);
  };
  auto stage_store = [&]() {
#pragma unroll
    for (int i = 0; i < 6; i++)
      *(bf16x8*)(Ks + krow[i]*LK + kcol[i]) = kreg[i];
#pragma unroll
    for (int i = 0; i < 4; i++)
      *(bf16x8*)(Vs + vrow[i]*LV + vcol[i]) = vreg[i];
  };

  bf16x8 qf[2][6];
#pragma unroll
  for (int s = 0; s < 2; s++) {
    const BF16* qp = Qb + (long)(q0 + s*64 + wave*16 + lr) * 192 + quad*8;
#pragma unroll
    for (int f = 0; f < 6; f++) qf[s][f] = *(const bf16x8*)(qp + f*32);
  }
  float m_i[2][4], l_i[2][4];
#pragma unroll
  for (int s = 0; s < 2; s++)
#pragma unroll
    for (int r = 0; r < 4; r++) { m_i[s][r] = NEG_INF; l_i[s][r] = 0.f; }
  floatx4 o_acc[2][8] = {};

  int nk = 2*qti + 2;
  stage_load(0);
  for (int kt = 0; kt < nk; kt++) {
    int k0 = kt * 64;
    __syncthreads();   // prev-iter LDS reads complete
    stage_store();
    __syncthreads();
    if (kt + 1 < nk) stage_load(k0 + 64);  // prefetch overlaps compute
#pragma unroll
    for (int s = 0; s < 2; s++) {
      int diag = 2*qti + s;
      if (kt > diag) continue;  // fragment fully masked (wave-uniform)
      floatx4 st[4];
#pragma unroll
      for (int t = 0; t < 4; t++) {
        floatx4 c = {};
#pragma unroll
        for (int f = 0; f < 6; f++) {
          bf16x8 kf = *(const bf16x8*)(Ks + (t*16+lr)*LK + f*32 + quad*8);
          c = __builtin_amdgcn_mfma_f32_16x16x32_bf16(qf[s][f], kf, c, 0, 0, 0);
        }
        st[t] = c;
      }
      float mt[4];
#pragma unroll
      for (int r = 0; r < 4; r++) mt[r] = NEG_INF;
      if (kt == diag) { // diagonal tile: causal mask (tile-local offsets)
#pragma unroll
        for (int t = 0; t < 4; t++) {
          int coff = t*16 + lr;
#pragma unroll
          for (int r = 0; r < 4; r++) {
            float sc = st[t][r];
            if (coff > wave*16 + quad*4 + r) sc = NEG_INF;
            st[t][r] = sc;
            mt[r] = fmaxf(mt[r], sc);
          }
        }
      } else {
#pragma unroll
        for (int t = 0; t < 4; t++)
#pragma unroll
          for (int r = 0; r < 4; r++) mt[r] = fmaxf(mt[r], st[t][r]);
      }
#pragma unroll
      for (int off = 1; off < 16; off <<= 1)
#pragma unroll
        for (int r = 0; r < 4; r++) mt[r] = fmaxf(mt[r], __shfl_xor(mt[r], off));
      float alpha[4], rsum[4];
#pragma unroll
      for (int r = 0; r < 4; r++) {
        float mn = fmaxf(m_i[s][r], mt[r]);
        alpha[r] = fast_exp2(m_i[s][r] - mn);
        m_i[s][r] = mn;
        rsum[r] = 0.f;
      }
#pragma unroll
      for (int t = 0; t < 4; t++)
#pragma unroll
        for (int r = 0; r < 4; r++) {
          float p = fast_exp2(st[t][r] - m_i[s][r]);
          st[t][r] = p;
          rsum[r] += p;
        }
#pragma unroll
      for (int off = 1; off < 16; off <<= 1)
#pragma unroll
        for (int r = 0; r < 4; r++) rsum[r] += __shfl_xor(rsum[r], off);
#pragma unroll
      for (int r = 0; r < 4; r++) l_i[s][r] = l_i[s][r]*alpha[r] + rsum[r];
#pragma unroll
      for (int v = 0; v < 8; v++)
#pragma unroll
        for (int r = 0; r < 4; r++) o_acc[s][v][r] *= alpha[r];
      // P (C-layout) -> wave-private LDS -> A-layout (no barrier: wave-level ordering)
#pragma unroll
      for (int t = 0; t < 4; t++)
#pragma unroll
        for (int r = 0; r < 4; r++)
          Ps[wave][(quad*4 + r)*LP + t*16 + lr] = f2b(st[t][r]);
#pragma unroll
      for (int kc = 0; kc < 2; kc++) {
        bf16x8 pa = *(const bf16x8*)(&Ps[wave][lr*LP + kc*32 + quad*8]);
#pragma unroll
        for (int v = 0; v < 8; v++) {
          bf16x8 vf = *(const bf16x8*)(&Vs[(v*16+lr)*LV + kc*32 + quad*8]);
          o_acc[s][v] = __builtin_amdgcn_mfma_f32_16x16x32_bf16(pa, vf, o_acc[s][v], 0, 0, 0);
        }
      }
    }
  }
#pragma unroll
  for (int s = 0; s < 2; s++) {
    long rowb = q0 + s*64 + wave*16 + quad*4;
#pragma unroll
    for (int v = 0; v < 8; v++)
#pragma unroll
      for (int r = 0; r < 4; r++) {
        long row = rowb + r;
        O[((long)b*2048 + row)*2048 + h*128 + v*16 + lr] = f2b(o_acc[s][v][r] / l_i[s][r]);
      }
  }
}

// ---------------------------------------------------------------- launch
extern "C" void kernel_launch(void* const* d_in, const int* in_sizes, int n_in,
                              void* d_out, int out_size, void* d_ws, size_t ws_size,
                              hipStream_t stream) {
  const float* hidden      = (const float*)d_in[0];
  const float* cosb        = (const float*)d_in[1];
  const float* sinb        = (const float*)d_in[2];
  const float* q_a_W       = (const float*)d_in[3];
  const float* q_a_norm_w  = (const float*)d_in[4];
  const float* q_b_W       = (const float*)d_in[5];
  const float* kv_a_W      = (const float*)d_in[6];
  const float* kv_a_norm_w = (const float*)d_in[7];
  const float* kv_b_W      = (const float*)d_in[8];
  const float* o_W         = (const float*)d_in[9];
  float* out = (float*)d_out;

  const int Mrows = 4096;

  char* ws = (char*)d_ws; size_t off = 0;
  auto alloc = [&](size_t bytes) -> void* {
    void* p = ws + off; off = (off + bytes + 255) & ~(size_t)255; return p;
  };
  BF16* hb    = (BF16*)alloc((size_t)4096*2048*2);
  BF16* Wqakv = (BF16*)alloc((size_t)2112*2048*2);   // rows 0..1536 = q_a_W, 1536..2112 = kv_a_W
  BF16* Wqb   = (BF16*)alloc((size_t)3072*1536*2);
  BF16* Wkvb  = (BF16*)alloc((size_t)4096*512*2);
  BF16* Wo    = (BF16*)alloc((size_t)2048*2048*2);
  float* qakv = (float*)alloc((size_t)4096*2112*4);  // cols 0..1536 = q_a out, 1536..2112 = ckv
  BF16* qan   = (BF16*)alloc((size_t)4096*1536*2);
  BF16* kvn   = (BF16*)alloc((size_t)4096*512*2);
  BF16* Qt    = (BF16*)alloc((size_t)2*16*2048*192*2);
  BF16* Kt    = (BF16*)alloc((size_t)2*16*2048*192*2);
  BF16* Vt    = (BF16*)alloc((size_t)2*16*128*2048*2); // transposed (B,H,128,S)
  BF16* attn  = (BF16*)alloc((size_t)4096*2048*2);

  CastArgs ca;
  ca.src[0] = hidden;  ca.dst[0] = hb;                 ca.n[0] = (long)4096*2048;
  ca.src[1] = q_a_W;   ca.dst[1] = Wqakv;              ca.n[1] = (long)1536*2048;
  ca.src[2] = kv_a_W;  ca.dst[2] = Wqakv + (long)1536*2048; ca.n[2] = (long)576*2048;
  ca.src[3] = q_b_W;   ca.dst[3] = Wqb;                ca.n[3] = (long)3072*1536;
  ca.src[4] = kv_b_W;  ca.dst[4] = Wkvb;               ca.n[4] = (long)4096*512;
  ca.src[5] = o_W;     ca.dst[5] = Wo;                 ca.n[5] = (long)2048*2048;
  cast_multi_k<<<dim3(1024, 6), dim3(256), 0, stream>>>(ca);

  // [q_a | ckv] = hidden @ [q_a_W | kv_a_W].T  (4096 x 2112, K=2048), fp32
  gemm_lds<0><<<dim3(17, 32), dim3(256), 0, stream>>>(hb, Wqakv, qakv, Mrows, 2112, 2048,
                                                      nullptr, nullptr, nullptr, nullptr);
  rmsnorm_k<1536><<<dim3(4096), dim3(256), 0, stream>>>(qakv, q_a_norm_w, qan, 2112, 1536);
  rmsnorm_k<512><<<dim3(4096), dim3(256), 0, stream>>>(qakv + 1536, kv_a_norm_w, kvn, 2112, 512);
  prep_krot_k<<<dim3(4096), dim3(64), 0, stream>>>(qakv + 2048, 2112, cosb, sinb, Kt);

  // q = qan @ q_b_W.T (4096x3072, K=1536), fused RoPE+scale -> Qt
  gemm_lds<3><<<dim3(24, 32), dim3(256), 0, stream>>>(qan, Wqb, nullptr, Mrows, 3072, 1536,
                                                      cosb, sinb, Qt, nullptr);
  // kv = kvn @ kv_b_W.T (4096x4096, K=512), fused scatter -> Kt / Vt^T
  gemm_lds<2><<<dim3(32, 32), dim3(256), 0, stream>>>(kvn, Wkvb, nullptr, Mrows, 4096, 512,
                                                      nullptr, nullptr, Kt, Vt);

  flash_k<<<dim3(512), dim3(256), 0, stream>>>(Qt, Kt, Vt, attn);

  // out = attn @ o_W.T (4096x2048, K=2048), fp32 -> d_out
  gemm_lds<0><<<dim3(16, 32), dim3(256), 0, stream>>>(attn, Wo, out, Mrows, 2048, 2048,
                                                      nullptr, nullptr, nullptr, nullptr);
}

// Round 7
// 490.371 us; speedup vs baseline: 1.1081x; 1.1081x over previous
//
#include <hip/hip_runtime.h>
#include <hip/hip_bf16.h>

// DeepSeek V3 MLA attention forward, MI355X (gfx950).
// B=2, S=2048, D=2048, H=16, NOPE=128, ROPE=64, VDIM=128, QKD=192.

typedef __bf16 bf16x8 __attribute__((ext_vector_type(8)));
typedef float floatx4 __attribute__((ext_vector_type(4)));
#define BF16 __hip_bfloat16

static __device__ __forceinline__ BF16 f2b(float x) { return __float2bfloat16(x); }
static __device__ __forceinline__ unsigned short b2u(BF16 x) { return *(unsigned short*)&x; }
static __device__ __forceinline__ float fast_exp2(float x) { return __builtin_amdgcn_exp2f(x); }

static __device__ __forceinline__ void load_lds16(const BF16* g, BF16* l) {
  __builtin_amdgcn_global_load_lds((__attribute__((address_space(1))) void*)(void*)g,
                                   (__attribute__((address_space(3))) void*)(void*)l,
                                   16, 0, 0);
}

// ---------------------------------------------------------------- multi-region cast f32->bf16
struct CastArgs {
  const float* src[6];
  BF16* dst[6];
  long n[6];
};
__global__ void cast_multi_k(CastArgs a) {
  int r = blockIdx.y;
  long n = a.n[r];
  const float* __restrict__ x = a.src[r];
  BF16* __restrict__ y = a.dst[r];
  for (long i = ((long)blockIdx.x * 256 + threadIdx.x) * 4; i + 3 < n;
       i += (long)gridDim.x * 1024) {
    float4 v = *(const float4*)(x + i);
    y[i+0] = f2b(v.x); y[i+1] = f2b(v.y); y[i+2] = f2b(v.z); y[i+3] = f2b(v.w);
  }
}

// ---------------------------------------------------------------- NT GEMM, m97-style LDS staging
// C[M][N] = A[M][K]*B[N][K]^T. 256 thr = 4 waves (2x2), 128x128 tile, BK=32.
// OUT_MODE: 0 = fp32 C;  2 = kv scatter -> Kt (scalar) / Vt transposed (8B packed);
//           3 = q RoPE+scale scatter -> Qt (scale includes log2(e) for exp2 softmax).
template<int OUT_MODE>
__global__ __launch_bounds__(256) void gemm_lds(const BF16* __restrict__ A, const BF16* __restrict__ B,
                                                void* __restrict__ C, int M, int N, int K,
                                                const float* __restrict__ cosb,
                                                const float* __restrict__ sinb,
                                                BF16* __restrict__ P1, BF16* __restrict__ P2) {
  __shared__ __align__(16) BF16 As[128*32];
  __shared__ __align__(16) BF16 Bs[128*32];
  int tid = threadIdx.x, wave = tid >> 6, lane = tid & 63;
  int wr = wave >> 1, wc = wave & 1, lr = lane & 15, quad = lane >> 4;
  long m0 = (long)blockIdx.y * 128, n0 = (long)blockIdx.x * 128;

  int c0 = wave*64 + lane, c1 = c0 + 256;
  const BF16* ga0 = A + (m0 + (c0>>2))*(long)K + (c0&3)*8;
  const BF16* ga1 = A + (m0 + (c1>>2))*(long)K + (c1&3)*8;
  long bn0 = n0 + (c0>>2); if (bn0 >= N) bn0 = N-1;
  long bn1 = n0 + (c1>>2); if (bn1 >= N) bn1 = N-1;
  const BF16* gb0 = B + bn0*(long)K + (c0&3)*8;
  const BF16* gb1 = B + bn1*(long)K + (c1&3)*8;
  BF16* la0 = As + wave*512;
  BF16* la1 = As + wave*512 + 2048;
  BF16* lb0 = Bs + wave*512;
  BF16* lb1 = Bs + wave*512 + 2048;

  floatx4 acc[4][4] = {};
  for (int k0 = 0; k0 < K; k0 += 32) {
    __syncthreads();
    load_lds16(ga0 + k0, la0);
    load_lds16(ga1 + k0, la1);
    load_lds16(gb0 + k0, lb0);
    load_lds16(gb1 + k0, lb1);
    __syncthreads();
    bf16x8 a[4], b[4];
#pragma unroll
    for (int i = 0; i < 4; i++) a[i] = *(const bf16x8*)(As + (wr*64 + i*16 + lr)*32 + quad*8);
#pragma unroll
    for (int j = 0; j < 4; j++) b[j] = *(const bf16x8*)(Bs + (wc*64 + j*16 + lr)*32 + quad*8);
#pragma unroll
    for (int i = 0; i < 4; i++)
#pragma unroll
      for (int j = 0; j < 4; j++)
        acc[i][j] = __builtin_amdgcn_mfma_f32_16x16x32_bf16(a[i], b[j], acc[i][j], 0, 0, 0);
  }

  long n0w = n0 + wc*64;
  // 192^-0.5 * log2(e): softmax runs in exp2 domain.
  const float SCALE_L2E = 0.104117546f;
#pragma unroll
  for (int i = 0; i < 4; i++) {
    long tok = m0 + wr*64 + i*16 + quad*4;   // 4 consecutive tokens (r=0..3)
    long bb = tok >> 11, s = tok & 2047;
    if (OUT_MODE == 0) {
#pragma unroll
      for (int r = 0; r < 4; r++) {
        long row = tok + r;
#pragma unroll
        for (int j = 0; j < 4; j++) {
          long col = n0w + j*16 + lr;
          if (col < N) ((float*)C)[row*(long)N + col] = acc[i][j][r];
        }
      }
    } else if (OUT_MODE == 2) {
#pragma unroll
      for (int j = 0; j < 4; j++) {
        long col = n0w + j*16 + lr;
        long h = col >> 8, d = col & 255;
        if (d < 128) {
#pragma unroll
          for (int r = 0; r < 4; r++)
            P1[((bb*16 + h)*2048 + s + r)*192 + d] = f2b(acc[i][j][r]);
        } else {
          // Vt transposed (B,H,128,2048): 4 consecutive tokens packed, 8B store
          ushort4 pk;
          pk.x = b2u(f2b(acc[i][j][0])); pk.y = b2u(f2b(acc[i][j][1]));
          pk.z = b2u(f2b(acc[i][j][2])); pk.w = b2u(f2b(acc[i][j][3]));
          *(ushort4*)(P2 + ((bb*16 + h)*128 + d - 128)*2048 + s) = pk;
        }
      }
    } else { // OUT_MODE == 3: q RoPE + scale -> Qt (B,H,S,192)
      bool rope = ((n0w % 192) == 128);
#pragma unroll
      for (int r = 0; r < 4; r++) {
        long row = tok + r;
#pragma unroll
        for (int j = 0; j < 4; j++) {
          long col = n0w + j*16 + lr;
          float x = acc[i][j][r], val;
          if (rope) {
            int id = j*16 + lr;
            float partner = acc[i][j^2][r];
            float rot = (j < 2) ? -partner : partner;
            val = x*cosb[row*64 + id] + rot*sinb[row*64 + id];
          } else {
            val = x;
          }
          long h = col / 192, d = col % 192;
          P1[((bb*16 + h)*2048 + s + r)*192 + d] = f2b(val * SCALE_L2E);
        }
      }
    }
  }
}

// ---------------------------------------------------------------- RMSNorm (row-wise), fp32 in, bf16 out
template<int D>
__global__ __launch_bounds__(256) void rmsnorm_k(const float* __restrict__ x, const float* __restrict__ w,
                                                 BF16* __restrict__ y, int ld_in, int ld_out) {
  long row = blockIdx.x;
  const float* xr = x + row * (long)ld_in;
  float ss = 0.f;
  for (int i = threadIdx.x * 4; i < D; i += 1024) {
    float4 v = *(const float4*)(xr + i);
    ss += v.x*v.x + v.y*v.y + v.z*v.z + v.w*v.w;
  }
#pragma unroll
  for (int off = 32; off > 0; off >>= 1) ss += __shfl_down(ss, off);
  __shared__ float red[4];
  if ((threadIdx.x & 63) == 0) red[threadIdx.x >> 6] = ss;
  __syncthreads();
  float tot = red[0] + red[1] + red[2] + red[3];
  float rs = rsqrtf(tot / (float)D + 1e-6f);
  BF16* yr = y + row * (long)ld_out;
  for (int i = threadIdx.x * 4; i < D; i += 1024) {
    float4 v = *(const float4*)(xr + i);
    yr[i+0] = f2b(v.x * w[i+0] * rs);
    yr[i+1] = f2b(v.y * w[i+1] * rs);
    yr[i+2] = f2b(v.z * w[i+2] * rs);
    yr[i+3] = f2b(v.w * w[i+3] * rs);
  }
}

// ---------------------------------------------------------------- RoPE on k_rot -> Kt[...,128:192] for all 16 heads
__global__ void prep_krot_k(const float* __restrict__ krot, int ld, const float* __restrict__ cosb,
                            const float* __restrict__ sinb, BF16* __restrict__ Kt) {
  long row = blockIdx.x; int i = threadIdx.x;
  const float* kr = krot + row * (long)ld;
  float x = kr[i];
  float rot = (i < 32) ? -kr[i + 32] : kr[i - 32];
  BF16 v = f2b(x * cosb[row*64 + i] + rot * sinb[row*64 + i]);
  long b = row >> 11, s = row & 2047;
  long base = ((b*16)*2048 + s)*192 + 128 + i;
#pragma unroll
  for (int h = 0; h < 16; h++) Kt[base + (long)h*2048*192] = v;
}

// ---------------------------------------------------------------- causal flash attention
// flat grid 512; g = F&31 = (b,h) group (pins group to XCD F%8); jidx = F>>5.
// Block handles q-tile pair {jidx, 31-jidx}: exactly 33 k-tile iters per block,
// 2 blocks/CU, uniform load (the r5 128-row split broke this -> 1.45x critical path).
// Q prescaled by 192^-0.5*log2e -> exp2 softmax. V stored transposed (B,H,128,S):
// staging is 4 b128 global + 4 b128 bank-uniform LDS writes (8 dw/bank exact).
#define LK 200
#define LV 72
#define LP 72
__global__ __launch_bounds__(256) void flash_k(const BF16* __restrict__ Qt, const BF16* __restrict__ Kt,
                                               const BF16* __restrict__ Vt, BF16* __restrict__ O) {
  __shared__ __align__(16) BF16 Ks[64*LK];    // K tile [kpos][d]
  __shared__ __align__(16) BF16 Vs[128*LV];   // V^T tile [vd][kpos]
  __shared__ __align__(16) BF16 Ps[4][16*LP]; // per-wave P fragment [q16][kpos]
  int tid = threadIdx.x, wave = tid >> 6, lane = tid & 63;
  int lr = lane & 15, quad = lane >> 4;
  int F = blockIdx.x;
  int g = F & 31, jidx = F >> 5;
  int h = g & 15, b = g >> 4;
  const BF16* Qb = Qt + ((long)(b*16 + h) * 2048) * 192;
  const BF16* Kb = Kt + ((long)(b*16 + h) * 2048) * 192;
  const BF16* Vb = Vt + ((long)(b*16 + h) * 128) * 2048;
  const float NEG_INF = -__builtin_inff();

  // staging geometry (fixed per thread)
  int krow[6], kcol[6];
#pragma unroll
  for (int i = 0; i < 6; i++) {
    int c = tid + 256*i;
    krow[i] = c / 24; kcol[i] = (c % 24) * 8;
  }
  int vrow[4], vcol[4];
#pragma unroll
  for (int i = 0; i < 4; i++) {
    int c = tid + 256*i;
    vrow[i] = c >> 3; vcol[i] = (c & 7) * 8;  // V^T tile: 128 d-rows x 64 kpos
  }

  bf16x8 kreg[6], vreg[4];
  auto stage_load = [&](int k0) {
#pragma unroll
    for (int i = 0; i < 6; i++)
      kreg[i] = *(const bf16x8*)(Kb + (long)(k0 + krow[i])*192 + kcol[i]);
#pragma unroll
    for (int i = 0; i < 4; i++)
      vreg[i] = *(const bf16x8*)(Vb + (long)vrow[i]*2048 + k0 + vcol[i]);
  };
  auto stage_store = [&]() {
#pragma unroll
    for (int i = 0; i < 6; i++)
      *(bf16x8*)(Ks + krow[i]*LK + kcol[i]) = kreg[i];
#pragma unroll
    for (int i = 0; i < 4; i++)
      *(bf16x8*)(Vs + vrow[i]*LV + vcol[i]) = vreg[i];
  };

  for (int half = 0; half < 2; half++) {
    int qt = (half == 0) ? jidx : 31 - jidx;
    int q0 = qt * 64;
    bf16x8 qf[6];
    {
      const BF16* qp = Qb + (long)(q0 + wave*16 + lr) * 192 + quad*8;
#pragma unroll
      for (int f = 0; f < 6; f++) qf[f] = *(const bf16x8*)(qp + f*32);
    }
    float m_i[4], l_i[4];
#pragma unroll
    for (int r = 0; r < 4; r++) { m_i[r] = NEG_INF; l_i[r] = 0.f; }
    floatx4 o_acc[8] = {};
    int nk = qt + 1;
    stage_load(0);
    for (int kt = 0; kt < nk; kt++) {
      __syncthreads();   // prev-iter LDS reads complete
      stage_store();
      __syncthreads();
      if (kt + 1 < nk) stage_load((kt + 1) * 64);  // prefetch overlaps compute
      floatx4 st[4];
#pragma unroll
      for (int t = 0; t < 4; t++) {
        floatx4 c = {};
#pragma unroll
        for (int f = 0; f < 6; f++) {
          bf16x8 kf = *(const bf16x8*)(Ks + (t*16+lr)*LK + f*32 + quad*8);
          c = __builtin_amdgcn_mfma_f32_16x16x32_bf16(qf[f], kf, c, 0, 0, 0);
        }
        st[t] = c;
      }
      float mt[4];
#pragma unroll
      for (int r = 0; r < 4; r++) mt[r] = NEG_INF;
      if (kt == qt) { // diagonal tile: causal mask (tile-local offsets)
#pragma unroll
        for (int t = 0; t < 4; t++) {
          int coff = t*16 + lr;
#pragma unroll
          for (int r = 0; r < 4; r++) {
            float sc = st[t][r];
            if (coff > wave*16 + quad*4 + r) sc = NEG_INF;
            st[t][r] = sc;
            mt[r] = fmaxf(mt[r], sc);
          }
        }
      } else {
#pragma unroll
        for (int t = 0; t < 4; t++)
#pragma unroll
          for (int r = 0; r < 4; r++) mt[r] = fmaxf(mt[r], st[t][r]);
      }
#pragma unroll
      for (int off = 1; off < 16; off <<= 1)
#pragma unroll
        for (int r = 0; r < 4; r++) mt[r] = fmaxf(mt[r], __shfl_xor(mt[r], off));
      float alpha[4], rsum[4];
#pragma unroll
      for (int r = 0; r < 4; r++) {
        float mn = fmaxf(m_i[r], mt[r]);
        alpha[r] = fast_exp2(m_i[r] - mn);
        m_i[r] = mn;
        rsum[r] = 0.f;
      }
#pragma unroll
      for (int t = 0; t < 4; t++)
#pragma unroll
        for (int r = 0; r < 4; r++) {
          float p = fast_exp2(st[t][r] - m_i[r]);
          st[t][r] = p;
          rsum[r] += p;
        }
#pragma unroll
      for (int off = 1; off < 16; off <<= 1)
#pragma unroll
        for (int r = 0; r < 4; r++) rsum[r] += __shfl_xor(rsum[r], off);
#pragma unroll
      for (int r = 0; r < 4; r++) l_i[r] = l_i[r]*alpha[r] + rsum[r];
#pragma unroll
      for (int v = 0; v < 8; v++)
#pragma unroll
        for (int r = 0; r < 4; r++) o_acc[v][r] *= alpha[r];
      // P (C-layout) -> wave-private LDS -> A-layout (no barrier: wave-level ordering)
#pragma unroll
      for (int t = 0; t < 4; t++)
#pragma unroll
        for (int r = 0; r < 4; r++)
          Ps[wave][(quad*4 + r)*LP + t*16 + lr] = f2b(st[t][r]);
#pragma unroll
      for (int kc = 0; kc < 2; kc++) {
        bf16x8 pa = *(const bf16x8*)(&Ps[wave][lr*LP + kc*32 + quad*8]);
#pragma unroll
        for (int v = 0; v < 8; v++) {
          bf16x8 vf = *(const bf16x8*)(&Vs[(v*16+lr)*LV + kc*32 + quad*8]);
          o_acc[v] = __builtin_amdgcn_mfma_f32_16x16x32_bf16(pa, vf, o_acc[v], 0, 0, 0);
        }
      }
    }
    // epilogue: attn out (B,S,H*128) bf16
    long rowb = q0 + wave*16 + quad*4;
#pragma unroll
    for (int v = 0; v < 8; v++)
#pragma unroll
      for (int r = 0; r < 4; r++) {
        long row = rowb + r;
        O[((long)b*2048 + row)*2048 + h*128 + v*16 + lr] = f2b(o_acc[v][r] / l_i[r]);
      }
  }
}

// ---------------------------------------------------------------- launch
extern "C" void kernel_launch(void* const* d_in, const int* in_sizes, int n_in,
                              void* d_out, int out_size, void* d_ws, size_t ws_size,
                              hipStream_t stream) {
  const float* hidden      = (const float*)d_in[0];
  const float* cosb        = (const float*)d_in[1];
  const float* sinb        = (const float*)d_in[2];
  const float* q_a_W       = (const float*)d_in[3];
  const float* q_a_norm_w  = (const float*)d_in[4];
  const float* q_b_W       = (const float*)d_in[5];
  const float* kv_a_W      = (const float*)d_in[6];
  const float* kv_a_norm_w = (const float*)d_in[7];
  const float* kv_b_W      = (const float*)d_in[8];
  const float* o_W         = (const float*)d_in[9];
  float* out = (float*)d_out;

  const int Mrows = 4096;

  char* ws = (char*)d_ws; size_t off = 0;
  auto alloc = [&](size_t bytes) -> void* {
    void* p = ws + off; off = (off + bytes + 255) & ~(size_t)255; return p;
  };
  BF16* hb    = (BF16*)alloc((size_t)4096*2048*2);
  BF16* Wqakv = (BF16*)alloc((size_t)2112*2048*2);   // rows 0..1536 = q_a_W, 1536..2112 = kv_a_W
  BF16* Wqb   = (BF16*)alloc((size_t)3072*1536*2);
  BF16* Wkvb  = (BF16*)alloc((size_t)4096*512*2);
  BF16* Wo    = (BF16*)alloc((size_t)2048*2048*2);
  float* qakv = (float*)alloc((size_t)4096*2112*4);  // cols 0..1536 = q_a out, 1536..2112 = ckv
  BF16* qan   = (BF16*)alloc((size_t)4096*1536*2);
  BF16* kvn   = (BF16*)alloc((size_t)4096*512*2);
  BF16* Qt    = (BF16*)alloc((size_t)2*16*2048*192*2);
  BF16* Kt    = (BF16*)alloc((size_t)2*16*2048*192*2);
  BF16* Vt    = (BF16*)alloc((size_t)2*16*128*2048*2); // transposed (B,H,128,S)
  BF16* attn  = (BF16*)alloc((size_t)4096*2048*2);

  CastArgs ca;
  ca.src[0] = hidden;  ca.dst[0] = hb;                 ca.n[0] = (long)4096*2048;
  ca.src[1] = q_a_W;   ca.dst[1] = Wqakv;              ca.n[1] = (long)1536*2048;
  ca.src[2] = kv_a_W;  ca.dst[2] = Wqakv + (long)1536*2048; ca.n[2] = (long)576*2048;
  ca.src[3] = q_b_W;   ca.dst[3] = Wqb;                ca.n[3] = (long)3072*1536;
  ca.src[4] = kv_b_W;  ca.dst[4] = Wkvb;               ca.n[4] = (long)4096*512;
  ca.src[5] = o_W;     ca.dst[5] = Wo;                 ca.n[5] = (long)2048*2048;
  cast_multi_k<<<dim3(1024, 6), dim3(256), 0, stream>>>(ca);

  // [q_a | ckv] = hidden @ [q_a_W | kv_a_W].T  (4096 x 2112, K=2048), fp32
  gemm_lds<0><<<dim3(17, 32), dim3(256), 0, stream>>>(hb, Wqakv, qakv, Mrows, 2112, 2048,
                                                      nullptr, nullptr, nullptr, nullptr);
  rmsnorm_k<1536><<<dim3(4096), dim3(256), 0, stream>>>(qakv, q_a_norm_w, qan, 2112, 1536);
  rmsnorm_k<512><<<dim3(4096), dim3(256), 0, stream>>>(qakv + 1536, kv_a_norm_w, kvn, 2112, 512);
  prep_krot_k<<<dim3(4096), dim3(64), 0, stream>>>(qakv + 2048, 2112, cosb, sinb, Kt);

  // q = qan @ q_b_W.T (4096x3072, K=1536), fused RoPE+scale -> Qt
  gemm_lds<3><<<dim3(24, 32), dim3(256), 0, stream>>>(qan, Wqb, nullptr, Mrows, 3072, 1536,
                                                      cosb, sinb, Qt, nullptr);
  // kv = kvn @ kv_b_W.T (4096x4096, K=512), fused scatter -> Kt / Vt^T
  gemm_lds<2><<<dim3(32, 32), dim3(256), 0, stream>>>(kvn, Wkvb, nullptr, Mrows, 4096, 512,
                                                      nullptr, nullptr, Kt, Vt);

  flash_k<<<dim3(512), dim3(256), 0, stream>>>(Qt, Kt, Vt, attn);

  // out = attn @ o_W.T (4096x2048, K=2048), fp32 -> d_out
  gemm_lds<0><<<dim3(16, 32), dim3(256), 0, stream>>>(attn, Wo, out, Mrows, 2048, 2048,
                                                      nullptr, nullptr, nullptr, nullptr);
}